// Round 2
// baseline (41290.903 us; speedup 1.0000x reference)
//
#include <hip/hip_runtime.h>

#define NB 8
#define T 32000
#define NLAYERS 30
#define RES 64
#define GATE 128
#define SKIPC 64
#define CIN 80
#define OUTC 256
#define TF 400
#define TM 4000

// packed weight layout:
//   per layer l: conv [i:64][tap:2][o:128] (16384) + cond [i:80][o:128] (10240) = LSTRIDE
//   then skip_wT [l][i:64][o:64], out_wT [l][i:64][o:64], last1T [i:64][o:64], last2T [i:64][o:256]
#define LSTRIDE 26624
#define SKT_OFF  (NLAYERS * LSTRIDE)            // 798720
#define OUTT_OFF (SKT_OFF + NLAYERS * 4096)     // 921600
#define L1T_OFF  (OUTT_OFF + NLAYERS * 4096)    // 1044480
#define L2T_OFF  (L1T_OFF + 4096)               // 1048576
#define PACK_FLOATS (L2T_OFF + 16384)           // 1064960

__global__ void pack_weights(const float* __restrict__ conv_w,
                             const float* __restrict__ cond_w,
                             const float* __restrict__ skip_w,
                             const float* __restrict__ out_w,
                             const float* __restrict__ last1_w,
                             const float* __restrict__ last2_w,
                             float* __restrict__ wp) {
    int e = blockIdx.x * 256 + threadIdx.x;
    if (e >= PACK_FLOATS) return;
    if (e < SKT_OFF) {
        int l = e / LSTRIDE, r = e % LSTRIDE;
        if (r < 16384) {
            int i = r >> 8, tap = (r >> 7) & 1, o = r & 127;
            wp[e] = conv_w[((l * GATE + o) * RES + i) * 2 + tap];
        } else {
            int r2 = r - 16384;
            int i = r2 >> 7, o = r2 & 127;
            wp[e] = cond_w[(l * GATE + o) * CIN + i];
        }
    } else if (e < OUTT_OFF) {
        int r = e - SKT_OFF;
        int l = r >> 12, r2 = r & 4095, i = r2 >> 6, o = r2 & 63;
        wp[e] = skip_w[(l * SKIPC + o) * 64 + i];
    } else if (e < L1T_OFF) {
        int r = e - OUTT_OFF;
        int l = r >> 12, r2 = r & 4095, i = r2 >> 6, o = r2 & 63;
        wp[e] = out_w[(l * RES + o) * 64 + i];
    } else if (e < L2T_OFF) {
        int r = e - L1T_OFF;
        int i = r >> 6, o = r & 63;
        wp[e] = last1_w[o * 64 + i];
    } else {
        int r = e - L2T_OFF;
        int i = r >> 8, o = r & 255;
        wp[e] = last2_w[o * 64 + i];
    }
}

__global__ void first_conv(const int* __restrict__ x, const float* __restrict__ fw,
                           const float* __restrict__ fb, float* __restrict__ h) {
    int tid = blockIdx.x * 256 + threadIdx.x;   // NB*T threads
    int b = tid / T, t = tid - b * T;
    int idx = x[tid];
    int base = (b * RES) * T + t;
    for (int o = 0; o < RES; ++o)
        h[base + o * T] = fw[o * OUTC + idx] + fb[o];
}

__global__ void cond_in(const float* __restrict__ cond, const float* __restrict__ cw,
                        float* __restrict__ c1) {
    int tid = blockIdx.x * blockDim.x + threadIdx.x;
    if (tid >= NB * TF) return;
    int b = tid / TF, t = tid - b * TF;
    for (int oc = 0; oc < CIN; oc += 20) {
        float acc[20];
#pragma unroll
        for (int j = 0; j < 20; ++j) acc[j] = 0.f;
        for (int i = 0; i < CIN; ++i) {
            float in = cond[(b * CIN + i) * TF + t];
#pragma unroll
            for (int j = 0; j < 20; ++j) acc[j] += cw[(oc + j) * CIN + i] * in;
        }
#pragma unroll
        for (int j = 0; j < 20; ++j) c1[(b * CIN + oc + j) * TF + t] = acc[j];
    }
}

__global__ void up1(const float* __restrict__ src, float* __restrict__ dst) {
    int tid = blockIdx.x * 256 + threadIdx.x;   // NB*CIN*TM
    int t = tid % TM, rc = tid / TM;
    const float* s = src + rc * TF;
    float acc = 0.f;
#pragma unroll
    for (int k = -10; k <= 10; ++k) {
        int j = t + k;
        if (j >= 0 && j < TM) acc += s[j / 10];
    }
    dst[tid] = acc * (1.f / 21.f);
}

__global__ void up2(const float* __restrict__ src, float* __restrict__ dst) {
    int tid = blockIdx.x * 256 + threadIdx.x;   // NB*CIN*T
    int t = tid % T, rc = tid / T;
    const float* s = src + rc * TM;
    float acc = 0.f;
#pragma unroll
    for (int k = -8; k <= 8; ++k) {
        int j = t + k;
        if (j >= 0 && j < T) acc += s[j >> 3];
    }
    dst[tid] = acc * (1.f / 17.f);
}

__device__ __forceinline__ float gatefn(float a, float bb) {
    a = fminf(fmaxf(a, -15.f), 15.f);
    bb = fminf(fmaxf(bb, -30.f), 30.f);
    float e2 = __expf(2.f * a);
    float th = (e2 - 1.f) / (e2 + 1.f);
    float sg = 1.f / (1.f + __expf(-bb));
    return th * sg;
}

__global__ __launch_bounds__(256, 2)
void layer_k(const float* __restrict__ h_in, float* __restrict__ h_out,
             float* __restrict__ skips, const float* __restrict__ c,
             const float* __restrict__ wp, const float* __restrict__ conv_b,
             const float* __restrict__ skip_b, const float* __restrict__ out_b,
             int l, int d, int first) {
    int tid = blockIdx.x * 256 + threadIdx.x;   // NB*T threads
    int b = tid / T, t = tid - b * T;
    const float* wl = wp + l * LSTRIDE;
    const float* cwl = wl + 16384;
    int hbase = (b * RES) * T + t;
    int cbase = (b * CIN) * T + t;
    const float* cb = conv_b + l * GATE;

    float z0[32], z1[32];

    // gate phase: two halves, each computing paired chunks (o, o+64) of g
#pragma unroll
    for (int half = 0; half < 2; ++half) {
        const int off = half * 32;
        float aa[32], ab[32];
#pragma unroll
        for (int j = 0; j < 32; ++j) { aa[j] = cb[off + j]; ab[j] = cb[64 + off + j]; }
        for (int i = 0; i < RES; ++i) {
            float a1 = h_in[hbase + i * T];
            float a0 = (t >= d) ? h_in[hbase + i * T - d] : 0.f;
            const float* w = wl + i * 256;
#pragma unroll
            for (int j = 0; j < 32; ++j) {
                aa[j] += w[off + j] * a0;
                ab[j] += w[64 + off + j] * a0;
            }
#pragma unroll
            for (int j = 0; j < 32; ++j) {
                aa[j] += w[128 + off + j] * a1;
                ab[j] += w[192 + off + j] * a1;
            }
        }
        for (int i = 0; i < CIN; ++i) {
            float ci = c[cbase + i * T];
            const float* w = cwl + i * 128;
#pragma unroll
            for (int j = 0; j < 32; ++j) {
                aa[j] += w[off + j] * ci;
                ab[j] += w[64 + off + j] * ci;
            }
        }
        if (half == 0) {
#pragma unroll
            for (int j = 0; j < 32; ++j) z0[j] = gatefn(aa[j], ab[j]);
        } else {
#pragma unroll
            for (int j = 0; j < 32; ++j) z1[j] = gatefn(aa[j], ab[j]);
        }
    }

    // projection phase: skip & residual, chunked by 32 output channels
    const float* skT = wp + SKT_OFF + l * 4096;
    const float* ouT = wp + OUTT_OFF + l * 4096;
    const float* sb = skip_b + l * SKIPC;
    const float* ob = out_b + l * RES;
    int sbase = (b * SKIPC) * T + t;
#pragma unroll
    for (int oc = 0; oc < 2; ++oc) {
        const int off = oc * 32;
        float accs[32], acch[32];
#pragma unroll
        for (int j = 0; j < 32; ++j) {
            accs[j] = sb[off + j];
            acch[j] = ob[off + j] + h_in[hbase + (off + j) * T];
        }
        for (int i = 0; i < 32; ++i) {
            float zi = z0[i];
            const float* sw = skT + i * 64 + off;
            const float* ow = ouT + i * 64 + off;
#pragma unroll
            for (int j = 0; j < 32; ++j) {
                accs[j] += sw[j] * zi;
                acch[j] += ow[j] * zi;
            }
        }
        for (int i = 0; i < 32; ++i) {
            float zi = z1[i];
            const float* sw = skT + (i + 32) * 64 + off;
            const float* ow = ouT + (i + 32) * 64 + off;
#pragma unroll
            for (int j = 0; j < 32; ++j) {
                accs[j] += sw[j] * zi;
                acch[j] += ow[j] * zi;
            }
        }
#pragma unroll
        for (int j = 0; j < 32; ++j) {
            int so = sbase + (off + j) * T;
            if (first) skips[so] = accs[j];
            else       skips[so] += accs[j];
            h_out[hbase + (off + j) * T] = acch[j];
        }
    }
}

__global__ __launch_bounds__(256, 2)
void final_k(const float* __restrict__ skips, const float* __restrict__ wp,
             const float* __restrict__ b1, const float* __restrict__ b2,
             float* __restrict__ out) {
    int tid = blockIdx.x * 256 + threadIdx.x;   // NB*T threads
    int b = tid / T, t = tid - b * T;
    const float* l1T = wp + L1T_OFF;
    const float* l2T = wp + L2T_OFF;
    int sbase = (b * SKIPC) * T + t;

    float y1[64];
#pragma unroll
    for (int o = 0; o < 64; ++o) y1[o] = b1[o];
    for (int i = 0; i < 64; ++i) {
        float s = fmaxf(skips[sbase + i * T], 0.f);
        const float* w = l1T + i * 64;
#pragma unroll
        for (int o = 0; o < 64; ++o) y1[o] += w[o] * s;
    }
#pragma unroll
    for (int o = 0; o < 64; ++o) y1[o] = fmaxf(y1[o], 0.f);

    int obase = (b * OUTC) * T + t;
#pragma unroll 1
    for (int oc = 0; oc < 8; ++oc) {
        const int off = oc * 32;
        float acc[32];
#pragma unroll
        for (int j = 0; j < 32; ++j) acc[j] = b2[off + j];
#pragma unroll
        for (int i = 0; i < 64; ++i) {
            float yi = y1[i];
            const float* w = l2T + i * 256 + off;
#pragma unroll
            for (int j = 0; j < 32; ++j) acc[j] += w[j] * yi;
        }
#pragma unroll
        for (int j = 0; j < 32; ++j) out[obase + (off + j) * T] = acc[j];
    }
}

extern "C" void kernel_launch(void* const* d_in, const int* in_sizes, int n_in,
                              void* d_out, int out_size, void* d_ws, size_t ws_size,
                              hipStream_t stream) {
    const int*   x       = (const int*)  d_in[0];
    const float* cond    = (const float*)d_in[1];
    const float* first_w = (const float*)d_in[2];
    const float* first_b = (const float*)d_in[3];
    const float* cin_w   = (const float*)d_in[4];
    const float* conv_w  = (const float*)d_in[5];
    const float* conv_b  = (const float*)d_in[6];
    const float* cond_w  = (const float*)d_in[7];
    const float* skip_w  = (const float*)d_in[8];
    const float* skip_b  = (const float*)d_in[9];
    const float* out_w   = (const float*)d_in[10];
    const float* out_b   = (const float*)d_in[11];
    const float* last1_w = (const float*)d_in[12];
    const float* last1_b = (const float*)d_in[13];
    const float* last2_w = (const float*)d_in[14];
    const float* last2_b = (const float*)d_in[15];
    float* out = (float*)d_out;

    // workspace layout (floats): skips | c | c2 | c1 | wpack   (~163 MB)
    float* ws    = (float*)d_ws;
    float* skips = ws;                                  // NB*SKIPC*T = 16,384,000
    float* c     = skips + NB * SKIPC * T;              // NB*CIN*T   = 20,480,000
    float* c2    = c     + NB * CIN * T;                // NB*CIN*TM  =  2,560,000
    float* c1    = c2    + NB * CIN * TM;               // NB*CIN*TF  =    256,000
    float* wpack = c1    + NB * CIN * TF;               // PACK_FLOATS=  1,064,960

    // h double-buffer lives inside d_out (dead by the time final_k writes)
    float* hA = out;
    float* hB = out + NB * RES * T;

    pack_weights<<<(PACK_FLOATS + 255) / 256, 256, 0, stream>>>(
        conv_w, cond_w, skip_w, out_w, last1_w, last2_w, wpack);
    first_conv<<<(NB * T) / 256, 256, 0, stream>>>(x, first_w, first_b, hA);
    cond_in<<<(NB * TF + 255) / 256, 256, 0, stream>>>(cond, cin_w, c1);
    up1<<<(NB * CIN * TM) / 256, 256, 0, stream>>>(c1, c2);
    up2<<<(NB * CIN * T) / 256, 256, 0, stream>>>(c2, c);

    for (int l = 0; l < NLAYERS; ++l) {
        int d = 1 << (l % 10);
        const float* h_in  = (l & 1) ? hB : hA;
        float*       h_out = (l & 1) ? hA : hB;
        layer_k<<<(NB * T) / 256, 256, 0, stream>>>(h_in, h_out, skips, c, wpack,
                                                    conv_b, skip_b, out_b,
                                                    l, d, (l == 0) ? 1 : 0);
    }
    final_k<<<(NB * T) / 256, 256, 0, stream>>>(skips, wpack, last1_b, last2_b, out);
}